// Round 7
// baseline (165.075 us; speedup 1.0000x reference)
//
#include <hip/hip_runtime.h>
#include <hip/hip_fp16.h>

// NeuronToSpatialGrid: out[b,e,p] = (sum_n w F[b,n,e]) / (sum_n w + 1e-8),
//   w = exp(-50 dx^2) * exp(-50 dy^2) (separable).
// R7: grid 512 = 64mt x 4b x 2et, 512 thr (8 waves = 4 ki K-quarters x 2 ni
// e-groups) -> 2 blocks/CU, 16 waves/CU, 4 waves/SIMD. Wave = 64m x 64e,
// K=1024 per wave. A = ex (LDS broadcast) * ey (LDS, BK=64 double-buffer,
// conflict-free staging), B direct from global in MFMA-frag chunks. One
// barrier per o-loop (32 MFMA/wave). Full K in block: in-block ki tree-combine
// through LDS (reuses EYs as 64 KB dump), normalized store direct to out.

typedef __attribute__((ext_vector_type(8))) _Float16 half8;
typedef __attribute__((ext_vector_type(2))) _Float16 half2v;
typedef __attribute__((ext_vector_type(4))) float floatx4;

#define NB 4
#define NN 4096
#define NE 256
#define NP 4096

#if defined(__has_builtin)
#if __has_builtin(__builtin_amdgcn_fdot2)
#define HAVE_FDOT2 1
#endif
#endif

__device__ inline float sum8(half8 v, float s) {
#ifdef HAVE_FDOT2
    half2v one; one[0] = (_Float16)1.0f; one[1] = (_Float16)1.0f;
    half2v* p = (half2v*)&v;
#pragma unroll
    for (int j = 0; j < 4; j++) s = __builtin_amdgcn_fdot2(p[j], one, s, false);
#else
#pragma unroll
    for (int j = 0; j < 8; j++) s += (float)v[j];
#endif
    return s;
}

#define MFMA16(a, bb, c) __builtin_amdgcn_mfma_f32_16x16x32_f16(a, bb, c, 0, 0, 0)

// ---------------- aux kernel ----------------
// bid < 1024: F[b][n][e] f32 -> FTf in B-frag chunk order:
//   chunk (b, kc 128, ec 16, quad 4, fr 16) of 8 halves = F[e=ec*16+fr][k=kc*32+quad*8+j].
// bid >= 1024 (512 blocks): EYf in A-frag chunk order:
//   chunk (b, kb 32, c 4, h 4, quad 4, fr 16) = exp(-50*((h*16+fr)/63 - y_k)^2), k=(kb*4+c)*32+quad*8+j.
__global__ __launch_bounds__(256) void aux_kernel(const float* __restrict__ in,
                                                  const float* __restrict__ pos,
                                                  __half* __restrict__ ftf,
                                                  __half* __restrict__ eyf) {
    const int bid = blockIdx.x;
    const int tid = threadIdx.x;
    if (bid < 1024) {
        __shared__ float tile[128][33];
        const int nb = bid & 31, eb = (bid >> 5) & 7, b = bid >> 8;
        const int n0 = nb * 128, e0 = eb * 32;
        const int rn = tid >> 3, re = (tid & 7) * 4;
#pragma unroll
        for (int p = 0; p < 4; p++) {
            const int n = p * 32 + rn;
            float4 v = *(const float4*)&in[(size_t)(b * NN + n0 + n) * NE + e0 + re];
            tile[n][re] = v.x; tile[n][re + 1] = v.y; tile[n][re + 2] = v.z; tile[n][re + 3] = v.w;
        }
        __syncthreads();
        const int kc_l = tid >> 6, quad = (tid >> 4) & 3, fr = tid & 15;
#pragma unroll
        for (int ec_l = 0; ec_l < 2; ec_l++) {
            half8 h;
#pragma unroll
            for (int j = 0; j < 8; j++)
                h[j] = (_Float16)tile[kc_l * 32 + quad * 8 + j][ec_l * 16 + fr];
            const size_t chunk = (((size_t)(b * 128 + nb * 4 + kc_l) * 16 + (eb * 2 + ec_l)) * 4 + quad) * 16 + fr;
            *(half8*)(ftf + chunk * 8) = h;
        }
    } else {
        const int idx = (bid - 1024) * 256 + tid;           // [0, 131072)
        const int fr = idx & 15;
        const int quad = (idx >> 4) & 3;
        const int h4 = (idx >> 6) & 3;
        const int c = (idx >> 8) & 3;
        const int kb = (idx >> 10) & 31;
        const int b = idx >> 15;
        const float gy = (float)(h4 * 16 + fr) * (1.0f / 63.0f);
        const int k0 = (kb * 4 + c) * 32 + quad * 8;
        const float* pb = pos + (size_t)b * NN * 2;
        half8 h;
#pragma unroll
        for (int j = 0; j < 8; j++) {
            const float d = gy - pb[(k0 + j) * 2 + 1];
            h[j] = (_Float16)__expf(d * d * -50.0f);
        }
        *(half8*)(eyf + (size_t)idx * 8) = h;
    }
}

// ---------------- main fused GEMM ----------------
// grid 512: et=bid&1, b=(bid>>1)&3 (xcd pin = bid&7), mt=bid>>3.
// 512 thr = 8 waves: ki = wave>>1 (K quarter of 1024), ni = wave&1 (e 64-group).
__global__ __launch_bounds__(512, 4) void nw_gemm(const __half* __restrict__ FTf,
                                                  const __half* __restrict__ EYf,
                                                  const float* __restrict__ pos,
                                                  float* __restrict__ out) {
    __shared__ __half EYs[4][2][4096];    // 4 ki x 2 buf x 8 KB = 64 KB (reused as epilogue dump)
    __shared__ __half ex_s[NN];           // 8 KB
    __shared__ float Spart[4][64];        // per-ki partial row sums
    __shared__ float Sinv[64];

    const int bid = blockIdx.x;
    const int et = bid & 1;
    const int b  = (bid >> 1) & 3;
    const int mt = bid >> 3;
    const int tid = threadIdx.x;

    // ex_s once per block (gx = mt constant): 8 exps/thread
    {
        const float gxv = (float)mt * (1.0f / 63.0f);
        const float2* pg = (const float2*)(pos + (size_t)b * NN * 2);
        for (int i = tid; i < NN; i += 512) {
            float d = gxv - pg[i].x;
            ex_s[i] = __float2half_rn(__expf(d * d * -50.0f));
        }
    }

    const int wave = tid >> 6, lane = tid & 63;
    const int ki = wave >> 1;             // K quarter: k in [ki*1024, ki*1024+1024)
    const int ni = wave & 1;              // e 64-group within et-half
    const int fr = lane & 15, quad = lane >> 4;

    // B source: frag chunk (b, kc = ki*32 + ss, ec = et*8 + ni*4 + jj), 1 KB, lane-contiguous
    const char* bbase = (const char*)FTf +
        (((size_t)(b * 128 + ki * 32) * 16 + (et * 8 + ni * 4)) << 10) + lane * 16;

    // ey staging: thread covers ki_s = tid>>7, t2 = tid&127; 4 x 16B, lane-contiguous writes
    const int ki_s = tid >> 7, t2 = tid & 127;
    const int soff = ((t2 >> 6) << 10) + (t2 & 63) * 16;   // bytes within 8 KB half (per w: +w*2048)
    const char* esrc = (const char*)EYf + ((size_t)b << 19) + ((size_t)ki_s << 17) + soff;

    floatx4 acc[4][4] = {};               // [h gy-frag][jj e-frag]
    float s0 = 0.f, s1 = 0.f;             // partial row sums: rows h = ni*2 + {0,1}

    // --- prologue: stage u=0 -> buf0; er <- u=1; bf[0] <- ss=0 ---
    uint4 er[4];
#pragma unroll
    for (int w = 0; w < 4; w++) er[w] = *(const uint4*)(esrc + w * 2048);
    {
        char* d = (char*)&EYs[ki_s][0][0] + soff;
#pragma unroll
        for (int w = 0; w < 4; w++) *(uint4*)(d + w * 2048) = er[w];
    }
#pragma unroll
    for (int w = 0; w < 4; w++) er[w] = *(const uint4*)(esrc + 8192 + w * 2048);

    uint4 bf[2][4];
#pragma unroll
    for (int jj = 0; jj < 4; jj++) bf[0][jj] = *(const uint4*)(bbase + (jj << 10));

    __syncthreads();                      // ex_s + EYs buf0 ready

    for (int o = 0; o < 16; o++) {
        const int buf = o & 1;
        const char* ebase = (const char*)&EYs[ki][buf][0] + lane * 16;
#pragma unroll
        for (int c = 0; c < 2; c++) {
            const int ss = o * 2 + c;
            const int par = ss & 1;
            // prefetch B for ss+1 (ping-pong)
            {
                const int nss = (ss + 1) & 31;
                const char* pn = bbase + ((size_t)nss << 14);
#pragma unroll
                for (int jj = 0; jj < 4; jj++)
                    bf[par ^ 1][jj] = *(const uint4*)(pn + (jj << 10));
            }
            // A-frags: ex (LDS broadcast) * ey (LDS, lane-contiguous, conflict-free)
            half8 ex8 = *(const half8*)(&ex_s[ki * 1024 + ss * 32 + quad * 8]);
            half8 af0 = ex8 * *(const half8*)(ebase + (c * 4 + 0) * 1024);
            half8 af1 = ex8 * *(const half8*)(ebase + (c * 4 + 1) * 1024);
            half8 af2 = ex8 * *(const half8*)(ebase + (c * 4 + 2) * 1024);
            half8 af3 = ex8 * *(const half8*)(ebase + (c * 4 + 3) * 1024);
            if (ni == 0) { s0 = sum8(af0, s0); s1 = sum8(af1, s1); }
            else         { s0 = sum8(af2, s0); s1 = sum8(af3, s1); }
#pragma unroll
            for (int jj = 0; jj < 4; jj++) {
                half8 bv = *(const half8*)&bf[par][jj];
                acc[0][jj] = MFMA16(af0, bv, acc[0][jj]);
                acc[1][jj] = MFMA16(af1, bv, acc[1][jj]);
                acc[2][jj] = MFMA16(af2, bv, acc[2][jj]);
                acc[3][jj] = MFMA16(af3, bv, acc[3][jj]);
            }
        }
        // write staged er (data for o+1) -> buf^1; prefetch er for o+2
        {
            char* d = (char*)&EYs[ki_s][buf ^ 1][0] + soff;
#pragma unroll
            for (int w = 0; w < 4; w++) *(uint4*)(d + w * 2048) = er[w];
            const int un = (o + 2 < 16) ? o + 2 : 15;
            const char* ps = esrc + un * 8192;
#pragma unroll
            for (int w = 0; w < 4; w++) er[w] = *(const uint4*)(ps + w * 2048);
        }
        __syncthreads();
    }

    // --- epilogue: in-block ki tree-combine; EYs reused as 64 KB dump ---
    // partial row sums: reduce over quad; rows gy = (ni*2+hh)*16 + fr
    s0 += __shfl_xor(s0, 16, 64); s0 += __shfl_xor(s0, 32, 64);
    s1 += __shfl_xor(s1, 16, 64); s1 += __shfl_xor(s1, 32, 64);
    if (quad == 0) {
        Spart[ki][ni * 32 + fr]      = s0;
        Spart[ki][ni * 32 + 16 + fr] = s1;
    }

    float* dump = (float*)&EYs[0][0][0];  // 16384 floats; region r = r*8192
    const int slotbase = ni * 4096 + lane * 4;   // frag f = ni*16+h*4+jj at f*256 + lane*4

    if (ki == 1 || ki == 3) {             // round 1: ki1 -> r0, ki3 -> r1
        float* d = dump + (ki >> 1) * 8192 + slotbase;
#pragma unroll
        for (int h = 0; h < 4; h++)
#pragma unroll
            for (int jj = 0; jj < 4; jj++)
                *(floatx4*)&d[(h * 4 + jj) * 256] = acc[h][jj];
    }
    __syncthreads();
    if (ki == 0 || ki == 2) {
        const float* d = dump + (ki >> 1) * 8192 + slotbase;
#pragma unroll
        for (int h = 0; h < 4; h++)
#pragma unroll
            for (int jj = 0; jj < 4; jj++) {
                floatx4 v = *(const floatx4*)&d[(h * 4 + jj) * 256];
                acc[h][jj].x += v.x; acc[h][jj].y += v.y;
                acc[h][jj].z += v.z; acc[h][jj].w += v.w;
            }
    }
    __syncthreads();
    if (ki == 2) {                        // round 2: ki2 -> r0
        float* d = dump + slotbase;
#pragma unroll
        for (int h = 0; h < 4; h++)
#pragma unroll
            for (int jj = 0; jj < 4; jj++)
                *(floatx4*)&d[(h * 4 + jj) * 256] = acc[h][jj];
    }
    if (tid < 64) {                       // total row sums -> 1/(S+eps)
        float t = Spart[0][tid] + Spart[1][tid] + Spart[2][tid] + Spart[3][tid];
        Sinv[tid] = 1.0f / (t + 1e-8f);
    }
    __syncthreads();
    if (ki == 0) {                        // combine + normalize + store
        const float* d = dump + slotbase;
        float* outb = out + (size_t)b * NE * NP;
#pragma unroll
        for (int h = 0; h < 4; h++) {
            floatx4 sv = *(const floatx4*)&Sinv[h * 16 + quad * 4];
#pragma unroll
            for (int jj = 0; jj < 4; jj++) {
                floatx4 v = *(const floatx4*)&d[(h * 4 + jj) * 256];
                floatx4 o = acc[h][jj];
                o.x = (o.x + v.x) * sv.x;
                o.y = (o.y + v.y) * sv.y;
                o.z = (o.z + v.z) * sv.z;
                o.w = (o.w + v.w) * sv.w;
                const int e = et * 128 + ni * 64 + jj * 16 + fr;
                *(floatx4*)&outb[(size_t)e * NP + mt * 64 + h * 16 + quad * 4] = o;
            }
        }
    }
}

extern "C" void kernel_launch(void* const* d_in, const int* in_sizes, int n_in,
                              void* d_out, int out_size, void* d_ws, size_t ws_size,
                              hipStream_t stream) {
    const float* feat = (const float*)d_in[0];   // [4][4096][256] f32
    const float* pos  = (const float*)d_in[1];   // [4][4096][2]  f32
    float* out = (float*)d_out;                  // [4][256][4096] f32

    char* ws = (char*)d_ws;
    __half* FTf = (__half*)ws;                   // 8,388,608 B
    __half* EYf = (__half*)(ws + 8388608);       // 2,097,152 B  (total 10.5 MB)

    hipLaunchKernelGGL(aux_kernel, dim3(1536), dim3(256), 0, stream, feat, pos, FTf, EYf);
    hipLaunchKernelGGL(nw_gemm, dim3(512), dim3(512), 0, stream, FTf, EYf, pos, out);
}